// Round 13
// baseline (318.929 us; speedup 1.0000x reference)
//
#include <hip/hip_runtime.h>

#define N_NODES 10000
#define N_EDGES 320000
#define INV3 0.5773502691896258f

typedef short short8 __attribute__((ext_vector_type(8)));
typedef float f32x4 __attribute__((ext_vector_type(4)));

__device__ __forceinline__ float gelu_f(float x) {
    // x * sigmoid(1.596(x+0.044715x^3)); rcp approx (~1 ulp) instead of IEEE div chain
    float x3 = x * x * x;
    float e = __expf(-1.5957691216057308f * (x + 0.044715f * x3));
    return x * __builtin_amdgcn_rcpf(1.0f + e);
}

__device__ __forceinline__ unsigned short f2bf(float f) {
    unsigned u = __float_as_uint(f);
    unsigned r = (u + 0x7FFFu + ((u >> 16) & 1u)) >> 16;
    return (unsigned short)r;
}
__device__ __forceinline__ float bf2f(unsigned short u) {
    return __uint_as_float(((unsigned)u) << 16);
}
__device__ __forceinline__ unsigned pk2(unsigned short lo, unsigned short hi) {
    return (unsigned)lo | ((unsigned)hi << 16);
}

// sum over the 16-lane row; result valid in lane 15 of each row (VALU DPP, no LDS)
__device__ __forceinline__ float rowsum16(float v) {
    v += __int_as_float(__builtin_amdgcn_update_dpp(0, __float_as_int(v), 0x118, 0xf, 0xf, true));
    v += __int_as_float(__builtin_amdgcn_update_dpp(0, __float_as_int(v), 0x114, 0xf, 0xf, true));
    v += __int_as_float(__builtin_amdgcn_update_dpp(0, __float_as_int(v), 0x112, 0xf, 0xf, true));
    v += __int_as_float(__builtin_amdgcn_update_dpp(0, __float_as_int(v), 0x111, 0xf, 0xf, true));
    return v;
}

// ---------------- combined pre-pass: hist (1250 blk) | prep_frags (9 blk) | node_l1 (2500 blk) ----------------
__global__ __launch_bounds__(256) void pre_kernel(
    const int* __restrict__ edge_dst, int* __restrict__ deg,
    const float* __restrict__ Wfc1, const float* __restrict__ Wfc2,
    const float* __restrict__ Wfc3, uint4* __restrict__ fragbuf,
    const float* __restrict__ node_input, const float* __restrict__ node_attr,
    const float* __restrict__ Wl1_0, const float* __restrict__ Wl1_1,
    unsigned short* __restrict__ f_sb, unsigned short* __restrict__ f_vb)
{
    const int b = blockIdx.x;
    if (b < 1250) {
        int e = b * 256 + threadIdx.x;
        if (e < N_EDGES) atomicAdd(&deg[edge_dst[e]], 1);
        return;
    }
    if (b < 1259) {
        const int tile = (b - 1250) * 4 + (threadIdx.x >> 6);
        if (tile >= 36) return;
        const int l = threadIdx.x & 63;
        const int e = l & 15, g = l >> 4;
        unsigned p[4] = {0u, 0u, 0u, 0u};
        if (tile < 4) {
            if (g == 0) {
                #pragma unroll
                for (int j = 0; j < 8; ++j) {
                    unsigned short bb = f2bf(Wfc1[j * 64 + tile * 16 + e]);
                    p[j >> 1] |= (unsigned)bb << (16 * (j & 1));
                }
            }
        } else if (tile < 12) {
            int t2 = tile - 4; int mt = t2 >> 1, kt = t2 & 1;
            #pragma unroll
            for (int j = 0; j < 8; ++j) {
                unsigned short bb = f2bf(Wfc2[(kt * 32 + g * 8 + j) * 64 + mt * 16 + e]);
                p[j >> 1] |= (unsigned)bb << (16 * (j & 1));
            }
        } else {
            int t3 = tile - 12; int mt3 = t3 >> 1, kt = t3 & 1;
            #pragma unroll
            for (int j = 0; j < 8; ++j) {
                unsigned short bb = f2bf(Wfc3[(kt * 32 + g * 8 + j) * 192 + mt3 * 16 + e]);
                p[j >> 1] |= (unsigned)bb << (16 * (j & 1));
            }
        }
        uint4 v; v.x = p[0]; v.y = p[1]; v.z = p[2]; v.w = p[3];
        fragbuf[tile * 64 + l] = v;
        return;
    }
    const int wid = threadIdx.x >> 6;
    const int t = threadIdx.x & 63;
    const int n = (b - 1259) * 4 + wid;
    __shared__ float x[4][160];
    const float* row = node_input + (size_t)n * 160;
    for (int i = t; i < 160; i += 64) x[wid][i] = row[i];
    const float a = node_attr[n];

    float acc = 0.f;
    for (int k = 0; k < 64; ++k) acc += x[wid][k] * Wl1_0[k * 64 + t];
    f_sb[(size_t)n * 64 + t] = f2bf(acc * (a * 0.125f));

    const float sv = a * 0.17677669529663687f;
    for (int o = t; o < 96; o += 64) {
        int w = o / 3, c = o - w * 3;
        float av = 0.f;
        for (int u = 0; u < 32; ++u) av += x[wid][64 + u * 3 + c] * Wl1_1[u * 32 + w];
        f_vb[(size_t)n * 96 + o] = f2bf(av * sv);
    }
}

__global__ __launch_bounds__(256) void alloc_kernel(const int* __restrict__ deg,
                                                    int* __restrict__ gctr,
                                                    int* __restrict__ rowptr,
                                                    int* __restrict__ cursor,
                                                    int* __restrict__ bcnt) {
    int n = blockIdx.x * 256 + threadIdx.x;
    if (n < N_NODES) {
        int d = deg[n];
        int base = atomicAdd(gctr, d);
        rowptr[n] = base;
        cursor[n] = base;
        int nt = (d + 15) >> 4; if (nt > 63) nt = 63;
        atomicAdd(&bcnt[nt], 1);
    }
}

__global__ __launch_bounds__(64) void bscan_kernel(const int* __restrict__ bcnt,
                                                   int* __restrict__ bcur) {
    if (threadIdx.x == 0) {
        int run = 0;
        for (int i = 63; i >= 0; --i) { bcur[i] = run; run += bcnt[i]; }  // descending nt
    }
}

// blocks [0,40): nodeperm scatter; [40,1290): elist scatter
__global__ __launch_bounds__(256) void post_kernel(const int* __restrict__ dst,
                                                   const int* __restrict__ deg,
                                                   int* __restrict__ cursor,
                                                   int* __restrict__ elist,
                                                   int* __restrict__ bcur,
                                                   int* __restrict__ nodeperm) {
    const int b = blockIdx.x;
    if (b < 40) {
        int n = b * 256 + threadIdx.x;
        if (n < N_NODES) {
            int nt = (deg[n] + 15) >> 4; if (nt > 63) nt = 63;
            int pos = atomicAdd(&bcur[nt], 1);
            nodeperm[pos] = n;
        }
        return;
    }
    int e = (b - 40) * 256 + threadIdx.x;
    if (e < N_EDGES) {
        int p = atomicAdd(&cursor[dst[e]], 1);
        elist[p] = e;
    }
}

// ---------------- fused node-centric kernel: wave pair per node, MLP deduplicated ----------------
#define L3CHUNK(mt3_, d_) { \
    short8 a0_ = ((short8*)wfrag)[(12 + (mt3_) * 2 + 0) * 64 + l]; \
    short8 a1_ = ((short8*)wfrag)[(12 + (mt3_) * 2 + 1) * 64 + l]; \
    d_[0] = 0.f; d_[1] = 0.f; d_[2] = 0.f; d_[3] = 0.f; \
    d_ = __builtin_amdgcn_mfma_f32_16x16x32_bf16(a0_, bh0, d_, 0, 0, 0); \
    d_ = __builtin_amdgcn_mfma_f32_16x16x32_bf16(a1_, bh1, d_, 0, 0, 0); }

__global__ __launch_bounds__(256) __attribute__((amdgpu_waves_per_eu(2, 4)))
void fused_kernel(
    const float* __restrict__ edge_attr,       // [E][4]
    const float* __restrict__ esa,             // [E][8]
    const unsigned short* __restrict__ f_sb,   // [N][64] bf16
    const unsigned short* __restrict__ f_vb,   // [N][96] bf16
    const int* __restrict__ edge_src,
    const int* __restrict__ elist,             // dst-sorted edge ids
    const int* __restrict__ rowptr,            // [N] segment starts
    const int* __restrict__ deg,               // [N] degrees
    const int* __restrict__ nodeperm,          // [N] degree-sorted node order
    const float4* __restrict__ fragbuf,        // 36 weight frag tiles
    const float* __restrict__ node_input,
    const float* __restrict__ node_attr,
    const float* __restrict__ Wsc0,
    const float* __restrict__ Wsc1,
    const float* __restrict__ Wl2_s,
    const float* __restrict__ Wl2_v,
    const float* __restrict__ Wa,
    float* __restrict__ out)
{
    __shared__ __align__(16) char wfrag[36864];    // all MLP weight frags (W1+W2+W3)
    __shared__ __align__(16) char albuf[2 * 4096]; // per node slot: h1 (2KB) + h2 (2KB); h1 reused as mid row
    __shared__ __align__(16) float xld[2][160];
    // LDS total = 36864 + 8192 + 1280 = 46336 B

    const int tid = threadIdx.x;
    const int l = tid & 63;
    const int wid = tid >> 6;
    const int q = wid & 1;       // channel/MLP-half of this wave
    const int ns = wid >> 1;     // node slot in block (0/1)

    {
        float4* w = (float4*)wfrag;
        #pragma unroll
        for (int i = 0; i < 9; ++i) w[tid + 256 * i] = fragbuf[tid + 256 * i];
    }

    const int n0 = nodeperm[blockIdx.x * 2 + 0];
    const int n1 = nodeperm[blockIdx.x * 2 + 1];
    const int n = ns ? n1 : n0;
    const int dn0 = deg[n0], dn1 = deg[n1];
    const int ntmax = ((dn0 > dn1 ? dn0 : dn1) + 15) >> 4;   // block-uniform trip count
    const int p0 = rowptr[n];
    const int p1 = p0 + (ns ? dn1 : dn0);
    const int p0c = p0 < N_EDGES ? p0 : N_EDGES - 1;         // safe dummy index

    if (q == 0)
        for (int i = l; i < 160; i += 64) xld[ns][i] = node_input[(size_t)n * 160 + i];

    __syncthreads();

    const int er = l & 15, gr = l >> 4;
    const int swz = (er & 7) << 4;
    char* h1b = albuf + ns * 4096;
    char* h2b = h1b + 2048;

    // half-channel accumulators (q selects jg in {2q,2q+1}, jv = q)
    float acc0[2][4];     // w0 -> mid_s[32q : 32q+32]
    float acc1[4];        // w3 -> mid_s[64+16q : 80+16q]
    float acc2[2][4][3];  // w1 -> mid_v first half per q
    float acc3[4][3];     // w2 -> mid_v second half per q
    #pragma unroll
    for (int jj = 0; jj < 2; ++jj)
        #pragma unroll
        for (int r = 0; r < 4; ++r) {
            acc0[jj][r] = 0.f;
            acc2[jj][r][0] = 0.f; acc2[jj][r][1] = 0.f; acc2[jj][r][2] = 0.f;
        }
    #pragma unroll
    for (int r = 0; r < 4; ++r) {
        acc1[r] = 0.f;
        acc3[r][0] = 0.f; acc3[r][1] = 0.f; acc3[r][2] = 0.f;
    }

    // ---- software-pipeline prologue: load iteration 0's edge data ----
    float4 ea = {0.f, 0.f, 0.f, 0.f};
    int src = 0;
    uint4 bxu = {0u, 0u, 0u, 0u};
    if (ntmax > 0) {
        const int ci = p0 + er;
        const bool cv = ci < p1;
        const int ec = elist[cv ? ci : p0c];
        ea = ((const float4*)edge_attr)[ec];
        src = edge_src[ec];
        if (l < 16 && cv) {
            float4 xa = ((const float4*)esa)[(size_t)ec * 2 + 0];
            float4 xb = ((const float4*)esa)[(size_t)ec * 2 + 1];
            bxu.x = pk2(f2bf(xa.x), f2bf(xa.y));
            bxu.y = pk2(f2bf(xa.z), f2bf(xa.w));
            bxu.z = pk2(f2bf(xb.x), f2bf(xb.y));
            bxu.w = pk2(f2bf(xb.z), f2bf(xb.w));
        }
    }

    #pragma unroll 1
    for (int it = 0; it < ntmax; ++it) {
        const float y0 = ea.x, y1a = ea.y, y1b = ea.z, y1c = ea.w;
        union { uint4 u; short8 s; } bxc; bxc.u = bxu;
        const short8 bx = bxc.s;
        const int csrc = src;

        // ---- issue this iteration's gathers (latency hides under L1/L2 MFMA) ----
        ushort4 gsu0 = *(const ushort4*)(f_sb + (size_t)csrc * 64 + (q * 2 + 0) * 16 + gr * 4);
        ushort4 gsu1 = *(const ushort4*)(f_sb + (size_t)csrc * 64 + (q * 2 + 1) * 16 + gr * 4);
        const unsigned short* gvp = f_vb + (size_t)csrc * 96 + (size_t)(q * 16 + gr * 4) * 3;
        ushort4 ga = *(const ushort4*)(gvp + 0);
        ushort4 gb = *(const ushort4*)(gvp + 4);
        ushort4 gc = *(const ushort4*)(gvp + 8);

        // ---- prefetch next iteration's edge data ----
        {
            const int np = p0 + (it + 1) * 16;
            const bool nv = (np + er) < p1;
            const int nec = elist[nv ? np + er : p0c];
            float4 nea = ((const float4*)edge_attr)[nec];
            int nsrc = edge_src[nec];
            uint4 nbxu = {0u, 0u, 0u, 0u};
            if (l < 16 && nv) {
                float4 xa = ((const float4*)esa)[(size_t)nec * 2 + 0];
                float4 xb = ((const float4*)esa)[(size_t)nec * 2 + 1];
                nbxu.x = pk2(f2bf(xa.x), f2bf(xa.y));
                nbxu.y = pk2(f2bf(xa.z), f2bf(xa.w));
                nbxu.z = pk2(f2bf(xb.x), f2bf(xb.y));
                nbxu.w = pk2(f2bf(xb.z), f2bf(xb.w));
            }
            ea = nea; src = nsrc; bxu = nbxu;
        }

        // ---- L1 (deduplicated: wave q computes mt=2q,2q+1 into shared h1) ----
        #pragma unroll
        for (int j = 0; j < 2; ++j) {
            const int mt = q * 2 + j;
            short8 aw = ((short8*)wfrag)[mt * 64 + l];
            f32x4 c = {0.f, 0.f, 0.f, 0.f};
            c = __builtin_amdgcn_mfma_f32_16x16x32_bf16(aw, bx, c, 0, 0, 0);
            unsigned pa = pk2(f2bf(gelu_f(c[0] * 0.35355339059327373f)),
                              f2bf(gelu_f(c[1] * 0.35355339059327373f)));
            unsigned pb = pk2(f2bf(gelu_f(c[2] * 0.35355339059327373f)),
                              f2bf(gelu_f(c[3] * 0.35355339059327373f)));
            uint2 pv; pv.x = pa; pv.y = pb;
            *(uint2*)(h1b + ((er * 128 + mt * 32 + gr * 8) ^ swz)) = pv;
        }
        __syncthreads();   // h1 complete (both waves)
        // ---- L2 (deduplicated: wave q computes mt=2q,2q+1 into shared h2) ----
        {
            short8 b0 = *(short8*)(h1b + ((er * 128 + 0  + gr * 16) ^ swz));
            short8 b1 = *(short8*)(h1b + ((er * 128 + 64 + gr * 16) ^ swz));
            #pragma unroll
            for (int j = 0; j < 2; ++j) {
                const int mt = q * 2 + j;
                short8 w2a = ((short8*)(wfrag + 4096))[(2 * mt + 0) * 64 + l];
                short8 w2b = ((short8*)(wfrag + 4096))[(2 * mt + 1) * 64 + l];
                f32x4 c = {0.f, 0.f, 0.f, 0.f};
                c = __builtin_amdgcn_mfma_f32_16x16x32_bf16(w2a, b0, c, 0, 0, 0);
                c = __builtin_amdgcn_mfma_f32_16x16x32_bf16(w2b, b1, c, 0, 0, 0);
                unsigned pa = pk2(f2bf(gelu_f(c[0] * 0.125f)), f2bf(gelu_f(c[1] * 0.125f)));
                unsigned pb = pk2(f2bf(gelu_f(c[2] * 0.125f)), f2bf(gelu_f(c[3] * 0.125f)));
                uint2 pv; pv.x = pa; pv.y = pb;
                *(uint2*)(h2b + ((er * 128 + mt * 32 + gr * 8) ^ swz)) = pv;
            }
        }
        __syncthreads();   // h2 complete (both waves)
        short8 bh0 = *(short8*)(h2b + ((er * 128 + 0  + gr * 16) ^ swz));
        short8 bh1 = *(short8*)(h2b + ((er * 128 + 64 + gr * 16) ^ swz));

        // ---- L3 + TP, only this wave's half of the channels ----
        #pragma unroll
        for (int jj = 0; jj < 2; ++jj) {
            const int jg = q * 2 + jj;
            ushort4 gsu = jj ? gsu1 : gsu0;
            f32x4 gs4 = {bf2f(gsu.x), bf2f(gsu.y), bf2f(gsu.z), bf2f(gsu.w)};
            f32x4 dA; L3CHUNK(jg, dA);
            f32x4 dB; L3CHUNK(jg + 4, dB);
            #pragma unroll
            for (int r = 0; r < 4; ++r) {
                acc0[jj][r] += 0.125f * dA[r] * gs4[r] * y0;
                float t_ = 0.125f * dB[r] * gs4[r];
                acc2[jj][r][0] += t_ * y1a;
                acc2[jj][r][1] += t_ * y1b;
                acc2[jj][r][2] += t_ * y1c;
            }
        }
        {
            const int jv = q;
            float gv[12] = {bf2f(ga.x), bf2f(ga.y), bf2f(ga.z), bf2f(ga.w),
                            bf2f(gb.x), bf2f(gb.y), bf2f(gb.z), bf2f(gb.w),
                            bf2f(gc.x), bf2f(gc.y), bf2f(gc.z), bf2f(gc.w)};
            f32x4 dC; L3CHUNK(8 + jv, dC);
            f32x4 dD; L3CHUNK(10 + jv, dD);
            #pragma unroll
            for (int r = 0; r < 4; ++r) {
                float w2v = 0.125f * dC[r] * y0;
                acc3[r][0] += w2v * gv[r * 3 + 0];
                acc3[r][1] += w2v * gv[r * 3 + 1];
                acc3[r][2] += w2v * gv[r * 3 + 2];
                float dot = gv[r * 3 + 0] * y1a + gv[r * 3 + 1] * y1b + gv[r * 3 + 2] * y1c;
                acc1[r] += 0.125f * dD[r] * dot * INV3;
            }
        }
    }

    // ---- column reduce (DPP); lane er==15 holds sums ----
    #pragma unroll
    for (int jj = 0; jj < 2; ++jj)
        #pragma unroll
        for (int r = 0; r < 4; ++r) {
            acc0[jj][r] = rowsum16(acc0[jj][r]);
            acc2[jj][r][0] = rowsum16(acc2[jj][r][0]);
            acc2[jj][r][1] = rowsum16(acc2[jj][r][1]);
            acc2[jj][r][2] = rowsum16(acc2[jj][r][2]);
        }
    #pragma unroll
    for (int r = 0; r < 4; ++r) {
        acc1[r] = rowsum16(acc1[r]);
        acc3[r][0] = rowsum16(acc3[r][0]);
        acc3[r][1] = rowsum16(acc3[r][1]);
        acc3[r][2] = rowsum16(acc3[r][2]);
    }

    __syncthreads();   // all K-loop LDS traffic done before mid-row aliasing

    // mid row for node slot ns aliases its h1 region (dead now): 384 floats = 1536 B
    float* m = (float*)(albuf + ns * 4096);
    const float iN = 0.17677669529663687f;   // 1/sqrt(NUM_NEIGHBORS)
    if (er == 15) {
        #pragma unroll
        for (int jj = 0; jj < 2; ++jj) {
            const int jg = q * 2 + jj;
            f32x4 v;
            v[0] = acc0[jj][0] * iN; v[1] = acc0[jj][1] * iN;
            v[2] = acc0[jj][2] * iN; v[3] = acc0[jj][3] * iN;
            *(f32x4*)(m + jg * 16 + gr * 4) = v;
        }
        {
            const int jv = q;
            f32x4 v;
            v[0] = acc1[0] * iN; v[1] = acc1[1] * iN;
            v[2] = acc1[2] * iN; v[3] = acc1[3] * iN;
            *(f32x4*)(m + 64 + jv * 16 + gr * 4) = v;
        }
        #pragma unroll
        for (int jj = 0; jj < 2; ++jj) {
            const int jg = q * 2 + jj;
            float t[12];
            #pragma unroll
            for (int r = 0; r < 4; ++r) {
                t[r * 3 + 0] = acc2[jj][r][0] * iN;
                t[r * 3 + 1] = acc2[jj][r][1] * iN;
                t[r * 3 + 2] = acc2[jj][r][2] * iN;
            }
            float* b = m + 96 + (jg * 16 + gr * 4) * 3;
            *(f32x4*)(b + 0) = (f32x4){t[0], t[1], t[2], t[3]};
            *(f32x4*)(b + 4) = (f32x4){t[4], t[5], t[6], t[7]};
            *(f32x4*)(b + 8) = (f32x4){t[8], t[9], t[10], t[11]};
        }
        {
            const int jv = q;
            float t[12];
            #pragma unroll
            for (int r = 0; r < 4; ++r) {
                t[r * 3 + 0] = acc3[r][0] * iN;
                t[r * 3 + 1] = acc3[r][1] * iN;
                t[r * 3 + 2] = acc3[r][2] * iN;
            }
            float* b = m + 288 + (jv * 16 + gr * 4) * 3;
            *(f32x4*)(b + 0) = (f32x4){t[0], t[1], t[2], t[3]};
            *(f32x4*)(b + 4) = (f32x4){t[4], t[5], t[6], t[7]};
            *(f32x4*)(b + 8) = (f32x4){t[8], t[9], t[10], t[11]};
        }
    }

    __syncthreads();   // mid row complete (written by both waves of the pair)

    // ---- fused linear2 + gate + self-connection; work split across the wave pair ----
    const float a = node_attr[n];
    const float* x = xld[ns];
    const float s96 = a * 0.10206207261596575f;

    float alpha = 0.f;
    for (int i = 0; i < 96; ++i) alpha += m[i] * Wa[i];
    alpha *= s96;

    if (q == 0) {
        float outs = 0.f;
        for (int i = 0; i < 96; ++i) outs += m[i] * Wl2_s[i * 64 + l];
        outs *= s96;
        float scs = 0.f;
        for (int k = 0; k < 64; ++k) scs += x[k] * Wsc0[k * 64 + l];
        scs *= a * 0.125f;
        out[(size_t)n * 160 + l] = scs + alpha * outs;
    } else {
        const float sv = a * 0.17677669529663687f;
        for (int o = l; o < 96; o += 64) {
            int w = o / 3, c = o - w * 3;
            float ov = 0.f;
            for (int u = 0; u < 64; ++u) ov += m[96 + u * 3 + c] * Wl2_v[u * 32 + w];
            for (int u = 0; u < 32; ++u) ov += m[288 + u * 3 + c] * Wl2_v[(64 + u) * 32 + w];
            ov *= s96;
            float scv = 0.f;
            for (int u = 0; u < 32; ++u) scv += x[64 + u * 3 + c] * Wsc1[u * 32 + w];
            scv *= sv;
            out[(size_t)n * 160 + 64 + o] = scv + alpha * ov;
        }
    }
}

extern "C" void kernel_launch(void* const* d_in, const int* in_sizes, int n_in,
                              void* d_out, int out_size, void* d_ws, size_t ws_size,
                              hipStream_t stream) {
    const float* node_input = (const float*)d_in[0];
    const float* node_attr  = (const float*)d_in[1];
    const float* edge_attr  = (const float*)d_in[2];
    const float* esa        = (const float*)d_in[3];
    const float* Wsc0       = (const float*)d_in[4];
    const float* Wsc1       = (const float*)d_in[5];
    const float* Wl1_0      = (const float*)d_in[6];
    const float* Wl1_1      = (const float*)d_in[7];
    const float* Wfc1       = (const float*)d_in[8];
    const float* Wfc2       = (const float*)d_in[9];
    const float* Wfc3       = (const float*)d_in[10];
    const float* Wl2_s      = (const float*)d_in[11];
    const float* Wl2_v      = (const float*)d_in[12];
    const float* Wa         = (const float*)d_in[13];
    const int* edge_src     = (const int*)d_in[14];
    const int* edge_dst     = (const int*)d_in[15];
    float* out = (float*)d_out;

    // ws layout: f_sb (bf16) | f_vb (bf16) | fragbuf | int CSR scratch + perm
    float* ws  = (float*)d_ws;
    unsigned short* f_sb = (unsigned short*)ws;                 // N*64 bf16
    unsigned short* f_vb = (unsigned short*)(ws + 320000);      // N*96 bf16
    uint4* fragbuf = (uint4*)(ws + 1600000);                    // 36*64 uint4
    int* ibuf     = (int*)(ws + 1609216);
    int* deg      = ibuf;            // 10000
    int* gctr     = ibuf + 10000;    // 1 (zeroed with deg)
    int* rowptr   = ibuf + 10016;    // 10000
    int* cursor   = ibuf + 20032;    // 10000
    int* elist    = ibuf + 30080;    // 320000 -> 350080
    int* bcnt     = ibuf + 350080;   // 64
    int* bcur     = ibuf + 350144;   // 64
    int* nodeperm = ibuf + 350208;   // 10000 -> 360208

    hipMemsetAsync(deg, 0, (size_t)(N_NODES + 1) * sizeof(int), stream);
    hipMemsetAsync(bcnt, 0, 64 * sizeof(int), stream);

    // pre_kernel: blocks [0,1250)=hist, [1250,1259)=prep_frags, [1259,3759)=node_l1
    pre_kernel<<<3759, 256, 0, stream>>>(edge_dst, deg, Wfc1, Wfc2, Wfc3, fragbuf,
                                         node_input, node_attr, Wl1_0, Wl1_1, f_sb, f_vb);
    alloc_kernel<<<(N_NODES + 255) / 256, 256, 0, stream>>>(deg, gctr, rowptr, cursor, bcnt);
    bscan_kernel<<<1, 64, 0, stream>>>(bcnt, bcur);
    post_kernel<<<40 + (N_EDGES + 255) / 256, 256, 0, stream>>>(edge_dst, deg, cursor,
                                                                elist, bcur, nodeperm);

    fused_kernel<<<N_NODES / 2, 256, 0, stream>>>(edge_attr, esa, f_sb, f_vb,
                                                  edge_src, elist, rowptr, deg, nodeperm,
                                                  (const float4*)fragbuf,
                                                  node_input, node_attr,
                                                  Wsc0, Wsc1, Wl2_s, Wl2_v, Wa,
                                                  out);
}

// Round 14
// 175.785 us; speedup vs baseline: 1.8143x; 1.8143x over previous
//
#include <hip/hip_runtime.h>

#define N_NODES 10000
#define N_EDGES 320000
#define INV3 0.5773502691896258f

typedef short short8 __attribute__((ext_vector_type(8)));
typedef float f32x4 __attribute__((ext_vector_type(4)));

__device__ __forceinline__ float gelu_f(float x) {
    // x * sigmoid(1.596(x+0.044715x^3)); rcp approx (~1 ulp) instead of IEEE div chain
    float x3 = x * x * x;
    float e = __expf(-1.5957691216057308f * (x + 0.044715f * x3));
    return x * __builtin_amdgcn_rcpf(1.0f + e);
}

__device__ __forceinline__ unsigned short f2bf(float f) {
    unsigned u = __float_as_uint(f);
    unsigned r = (u + 0x7FFFu + ((u >> 16) & 1u)) >> 16;
    return (unsigned short)r;
}
__device__ __forceinline__ float bf2f(unsigned short u) {
    return __uint_as_float(((unsigned)u) << 16);
}
__device__ __forceinline__ unsigned pk2(unsigned short lo, unsigned short hi) {
    return (unsigned)lo | ((unsigned)hi << 16);
}

// sum over the 16-lane row; result valid in lane 15 of each row (VALU DPP, no LDS)
__device__ __forceinline__ float rowsum16(float v) {
    v += __int_as_float(__builtin_amdgcn_update_dpp(0, __float_as_int(v), 0x118, 0xf, 0xf, true));
    v += __int_as_float(__builtin_amdgcn_update_dpp(0, __float_as_int(v), 0x114, 0xf, 0xf, true));
    v += __int_as_float(__builtin_amdgcn_update_dpp(0, __float_as_int(v), 0x112, 0xf, 0xf, true));
    v += __int_as_float(__builtin_amdgcn_update_dpp(0, __float_as_int(v), 0x111, 0xf, 0xf, true));
    return v;
}

// ---------------- combined pre-pass: hist (1250 blk) | prep_frags (9 blk) | node_l1 (2500 blk) ----------------
__global__ __launch_bounds__(256) void pre_kernel(
    const int* __restrict__ edge_dst, int* __restrict__ deg,
    const float* __restrict__ Wfc1, const float* __restrict__ Wfc2,
    const float* __restrict__ Wfc3, uint4* __restrict__ fragbuf,
    const float* __restrict__ node_input, const float* __restrict__ node_attr,
    const float* __restrict__ Wl1_0, const float* __restrict__ Wl1_1,
    unsigned short* __restrict__ f_sb, unsigned short* __restrict__ f_vb)
{
    const int b = blockIdx.x;
    if (b < 1250) {
        int e = b * 256 + threadIdx.x;
        if (e < N_EDGES) atomicAdd(&deg[edge_dst[e]], 1);
        return;
    }
    if (b < 1259) {
        const int tile = (b - 1250) * 4 + (threadIdx.x >> 6);
        if (tile >= 36) return;
        const int l = threadIdx.x & 63;
        const int e = l & 15, g = l >> 4;
        unsigned p[4] = {0u, 0u, 0u, 0u};
        if (tile < 4) {
            if (g == 0) {
                #pragma unroll
                for (int j = 0; j < 8; ++j) {
                    unsigned short bb = f2bf(Wfc1[j * 64 + tile * 16 + e]);
                    p[j >> 1] |= (unsigned)bb << (16 * (j & 1));
                }
            }
        } else if (tile < 12) {
            int t2 = tile - 4; int mt = t2 >> 1, kt = t2 & 1;
            #pragma unroll
            for (int j = 0; j < 8; ++j) {
                unsigned short bb = f2bf(Wfc2[(kt * 32 + g * 8 + j) * 64 + mt * 16 + e]);
                p[j >> 1] |= (unsigned)bb << (16 * (j & 1));
            }
        } else {
            int t3 = tile - 12; int mt3 = t3 >> 1, kt = t3 & 1;
            #pragma unroll
            for (int j = 0; j < 8; ++j) {
                unsigned short bb = f2bf(Wfc3[(kt * 32 + g * 8 + j) * 192 + mt3 * 16 + e]);
                p[j >> 1] |= (unsigned)bb << (16 * (j & 1));
            }
        }
        uint4 v; v.x = p[0]; v.y = p[1]; v.z = p[2]; v.w = p[3];
        fragbuf[tile * 64 + l] = v;
        return;
    }
    const int wid = threadIdx.x >> 6;
    const int t = threadIdx.x & 63;
    const int n = (b - 1259) * 4 + wid;
    __shared__ float x[4][160];
    const float* row = node_input + (size_t)n * 160;
    for (int i = t; i < 160; i += 64) x[wid][i] = row[i];
    const float a = node_attr[n];

    float acc = 0.f;
    for (int k = 0; k < 64; ++k) acc += x[wid][k] * Wl1_0[k * 64 + t];
    f_sb[(size_t)n * 64 + t] = f2bf(acc * (a * 0.125f));

    const float sv = a * 0.17677669529663687f;
    for (int o = t; o < 96; o += 64) {
        int w = o / 3, c = o - w * 3;
        float av = 0.f;
        for (int u = 0; u < 32; ++u) av += x[wid][64 + u * 3 + c] * Wl1_1[u * 32 + w];
        f_vb[(size_t)n * 96 + o] = f2bf(av * sv);
    }
}

// CSR alloc: block prefix-scan -> 1 gctr atomic per block; LDS-aggregated bucket counts
__global__ __launch_bounds__(256) void alloc_kernel(const int* __restrict__ deg,
                                                    int* __restrict__ gctr,
                                                    int* __restrict__ rowptr,
                                                    int* __restrict__ cursor,
                                                    int* __restrict__ bcnt) {
    const int tid = threadIdx.x;
    const int n = blockIdx.x * 256 + tid;
    const int d = (n < N_NODES) ? deg[n] : 0;

    __shared__ int part[256];
    __shared__ int blockbase;
    __shared__ int lb[64];
    part[tid] = d;
    if (tid < 64) lb[tid] = 0;
    __syncthreads();
    for (int o = 1; o < 256; o <<= 1) {
        int v = (tid >= o) ? part[tid - o] : 0;
        __syncthreads();
        part[tid] += v;
        __syncthreads();
    }
    if (tid == 255) blockbase = atomicAdd(gctr, part[255]);
    __syncthreads();
    const int base = blockbase + part[tid] - d;
    if (n < N_NODES) {
        rowptr[n] = base;
        cursor[n] = base;
        int nt = (d + 15) >> 4; if (nt > 63) nt = 63;
        atomicAdd(&lb[nt], 1);            // LDS atomic (cheap)
    }
    __syncthreads();
    if (tid < 64 && lb[tid]) atomicAdd(&bcnt[tid], lb[tid]);   // <=64 spread atomics/block
}

__global__ __launch_bounds__(64) void bscan_kernel(const int* __restrict__ bcnt,
                                                   int* __restrict__ bcur) {
    if (threadIdx.x == 0) {
        int run = 0;
        for (int i = 63; i >= 0; --i) { bcur[i] = run; run += bcnt[i]; }  // descending nt
    }
}

// blocks [0,40): nodeperm scatter (LDS-aggregated); [40,1290): elist scatter
__global__ __launch_bounds__(256) void post_kernel(const int* __restrict__ dst,
                                                   const int* __restrict__ deg,
                                                   int* __restrict__ cursor,
                                                   int* __restrict__ elist,
                                                   int* __restrict__ bcur,
                                                   int* __restrict__ nodeperm) {
    const int b = blockIdx.x;
    if (b < 40) {
        const int tid = threadIdx.x;
        const int n = b * 256 + tid;
        __shared__ int lcnt[64], lbase[64];
        if (tid < 64) lcnt[tid] = 0;
        __syncthreads();
        int nt = 63, my = 0;
        if (n < N_NODES) {
            int d = deg[n];
            nt = (d + 15) >> 4; if (nt > 63) nt = 63;
            my = atomicAdd(&lcnt[nt], 1);          // LDS atomic: local rank
        }
        __syncthreads();
        if (tid < 64 && lcnt[tid]) lbase[tid] = atomicAdd(&bcur[tid], lcnt[tid]);
        __syncthreads();
        if (n < N_NODES) nodeperm[lbase[nt] + my] = n;
        return;
    }
    int e = (b - 40) * 256 + threadIdx.x;
    if (e < N_EDGES) {
        int p = atomicAdd(&cursor[dst[e]], 1);     // spread over 10k addresses: fine
        elist[p] = e;
    }
}

// ---------------- fused node-centric kernel: wave pair per node, MLP deduplicated ----------------
#define L3CHUNK(mt3_, d_) { \
    short8 a0_ = ((short8*)wfrag)[(12 + (mt3_) * 2 + 0) * 64 + l]; \
    short8 a1_ = ((short8*)wfrag)[(12 + (mt3_) * 2 + 1) * 64 + l]; \
    d_[0] = 0.f; d_[1] = 0.f; d_[2] = 0.f; d_[3] = 0.f; \
    d_ = __builtin_amdgcn_mfma_f32_16x16x32_bf16(a0_, bh0, d_, 0, 0, 0); \
    d_ = __builtin_amdgcn_mfma_f32_16x16x32_bf16(a1_, bh1, d_, 0, 0, 0); }

__global__ __launch_bounds__(256) __attribute__((amdgpu_waves_per_eu(2, 4)))
void fused_kernel(
    const float* __restrict__ edge_attr,       // [E][4]
    const float* __restrict__ esa,             // [E][8]
    const unsigned short* __restrict__ f_sb,   // [N][64] bf16
    const unsigned short* __restrict__ f_vb,   // [N][96] bf16
    const int* __restrict__ edge_src,
    const int* __restrict__ elist,             // dst-sorted edge ids
    const int* __restrict__ rowptr,            // [N] segment starts
    const int* __restrict__ deg,               // [N] degrees
    const int* __restrict__ nodeperm,          // [N] degree-sorted node order
    const float4* __restrict__ fragbuf,        // 36 weight frag tiles
    const float* __restrict__ node_input,
    const float* __restrict__ node_attr,
    const float* __restrict__ Wsc0,
    const float* __restrict__ Wsc1,
    const float* __restrict__ Wl2_s,
    const float* __restrict__ Wl2_v,
    const float* __restrict__ Wa,
    float* __restrict__ out)
{
    __shared__ __align__(16) char wfrag[36864];    // all MLP weight frags (W1+W2+W3)
    __shared__ __align__(16) char albuf[2 * 4096]; // per node slot: h1 (2KB) + h2 (2KB); h1 reused as mid row
    __shared__ __align__(16) float xld[2][160];
    // LDS total = 36864 + 8192 + 1280 = 46336 B

    const int tid = threadIdx.x;
    const int l = tid & 63;
    const int wid = tid >> 6;
    const int q = wid & 1;       // channel/MLP-half of this wave
    const int ns = wid >> 1;     // node slot in block (0/1)

    {
        float4* w = (float4*)wfrag;
        #pragma unroll
        for (int i = 0; i < 9; ++i) w[tid + 256 * i] = fragbuf[tid + 256 * i];
    }

    const int n0 = nodeperm[blockIdx.x * 2 + 0];
    const int n1 = nodeperm[blockIdx.x * 2 + 1];
    const int n = ns ? n1 : n0;
    const int dn0 = deg[n0], dn1 = deg[n1];
    const int ntmax = ((dn0 > dn1 ? dn0 : dn1) + 15) >> 4;   // block-uniform trip count
    const int p0 = rowptr[n];
    const int p1 = p0 + (ns ? dn1 : dn0);
    const int p0c = p0 < N_EDGES ? p0 : N_EDGES - 1;         // safe dummy index

    if (q == 0)
        for (int i = l; i < 160; i += 64) xld[ns][i] = node_input[(size_t)n * 160 + i];

    __syncthreads();

    const int er = l & 15, gr = l >> 4;
    const int swz = (er & 7) << 4;
    char* h1b = albuf + ns * 4096;
    char* h2b = h1b + 2048;

    // half-channel accumulators (q selects jg in {2q,2q+1}, jv = q)
    float acc0[2][4];     // w0 -> mid_s[32q : 32q+32]
    float acc1[4];        // w3 -> mid_s[64+16q : 80+16q]
    float acc2[2][4][3];  // w1 -> mid_v first half per q
    float acc3[4][3];     // w2 -> mid_v second half per q
    #pragma unroll
    for (int jj = 0; jj < 2; ++jj)
        #pragma unroll
        for (int r = 0; r < 4; ++r) {
            acc0[jj][r] = 0.f;
            acc2[jj][r][0] = 0.f; acc2[jj][r][1] = 0.f; acc2[jj][r][2] = 0.f;
        }
    #pragma unroll
    for (int r = 0; r < 4; ++r) {
        acc1[r] = 0.f;
        acc3[r][0] = 0.f; acc3[r][1] = 0.f; acc3[r][2] = 0.f;
    }

    // ---- software-pipeline prologue: load iteration 0's edge data ----
    float4 ea = {0.f, 0.f, 0.f, 0.f};
    int src = 0;
    uint4 bxu = {0u, 0u, 0u, 0u};
    if (ntmax > 0) {
        const int ci = p0 + er;
        const bool cv = ci < p1;
        const int ec = elist[cv ? ci : p0c];
        ea = ((const float4*)edge_attr)[ec];
        src = edge_src[ec];
        if (l < 16 && cv) {
            float4 xa = ((const float4*)esa)[(size_t)ec * 2 + 0];
            float4 xb = ((const float4*)esa)[(size_t)ec * 2 + 1];
            bxu.x = pk2(f2bf(xa.x), f2bf(xa.y));
            bxu.y = pk2(f2bf(xa.z), f2bf(xa.w));
            bxu.z = pk2(f2bf(xb.x), f2bf(xb.y));
            bxu.w = pk2(f2bf(xb.z), f2bf(xb.w));
        }
    }

    #pragma unroll 1
    for (int it = 0; it < ntmax; ++it) {
        const float y0 = ea.x, y1a = ea.y, y1b = ea.z, y1c = ea.w;
        union { uint4 u; short8 s; } bxc; bxc.u = bxu;
        const short8 bx = bxc.s;
        const int csrc = src;

        // ---- issue this iteration's gathers (latency hides under L1/L2 MFMA) ----
        ushort4 gsu0 = *(const ushort4*)(f_sb + (size_t)csrc * 64 + (q * 2 + 0) * 16 + gr * 4);
        ushort4 gsu1 = *(const ushort4*)(f_sb + (size_t)csrc * 64 + (q * 2 + 1) * 16 + gr * 4);
        const unsigned short* gvp = f_vb + (size_t)csrc * 96 + (size_t)(q * 16 + gr * 4) * 3;
        ushort4 ga = *(const ushort4*)(gvp + 0);
        ushort4 gb = *(const ushort4*)(gvp + 4);
        ushort4 gc = *(const ushort4*)(gvp + 8);

        // ---- prefetch next iteration's edge data ----
        {
            const int np = p0 + (it + 1) * 16;
            const bool nv = (np + er) < p1;
            const int nec = elist[nv ? np + er : p0c];
            float4 nea = ((const float4*)edge_attr)[nec];
            int nsrc = edge_src[nec];
            uint4 nbxu = {0u, 0u, 0u, 0u};
            if (l < 16 && nv) {
                float4 xa = ((const float4*)esa)[(size_t)nec * 2 + 0];
                float4 xb = ((const float4*)esa)[(size_t)nec * 2 + 1];
                nbxu.x = pk2(f2bf(xa.x), f2bf(xa.y));
                nbxu.y = pk2(f2bf(xa.z), f2bf(xa.w));
                nbxu.z = pk2(f2bf(xb.x), f2bf(xb.y));
                nbxu.w = pk2(f2bf(xb.z), f2bf(xb.w));
            }
            ea = nea; src = nsrc; bxu = nbxu;
        }

        // ---- L1 (deduplicated: wave q computes mt=2q,2q+1 into shared h1) ----
        #pragma unroll
        for (int j = 0; j < 2; ++j) {
            const int mt = q * 2 + j;
            short8 aw = ((short8*)wfrag)[mt * 64 + l];
            f32x4 c = {0.f, 0.f, 0.f, 0.f};
            c = __builtin_amdgcn_mfma_f32_16x16x32_bf16(aw, bx, c, 0, 0, 0);
            unsigned pa = pk2(f2bf(gelu_f(c[0] * 0.35355339059327373f)),
                              f2bf(gelu_f(c[1] * 0.35355339059327373f)));
            unsigned pb = pk2(f2bf(gelu_f(c[2] * 0.35355339059327373f)),
                              f2bf(gelu_f(c[3] * 0.35355339059327373f)));
            uint2 pv; pv.x = pa; pv.y = pb;
            *(uint2*)(h1b + ((er * 128 + mt * 32 + gr * 8) ^ swz)) = pv;
        }
        __syncthreads();   // h1 complete (both waves)
        // ---- L2 (deduplicated: wave q computes mt=2q,2q+1 into shared h2) ----
        {
            short8 b0 = *(short8*)(h1b + ((er * 128 + 0  + gr * 16) ^ swz));
            short8 b1 = *(short8*)(h1b + ((er * 128 + 64 + gr * 16) ^ swz));
            #pragma unroll
            for (int j = 0; j < 2; ++j) {
                const int mt = q * 2 + j;
                short8 w2a = ((short8*)(wfrag + 4096))[(2 * mt + 0) * 64 + l];
                short8 w2b = ((short8*)(wfrag + 4096))[(2 * mt + 1) * 64 + l];
                f32x4 c = {0.f, 0.f, 0.f, 0.f};
                c = __builtin_amdgcn_mfma_f32_16x16x32_bf16(w2a, b0, c, 0, 0, 0);
                c = __builtin_amdgcn_mfma_f32_16x16x32_bf16(w2b, b1, c, 0, 0, 0);
                unsigned pa = pk2(f2bf(gelu_f(c[0] * 0.125f)), f2bf(gelu_f(c[1] * 0.125f)));
                unsigned pb = pk2(f2bf(gelu_f(c[2] * 0.125f)), f2bf(gelu_f(c[3] * 0.125f)));
                uint2 pv; pv.x = pa; pv.y = pb;
                *(uint2*)(h2b + ((er * 128 + mt * 32 + gr * 8) ^ swz)) = pv;
            }
        }
        __syncthreads();   // h2 complete (both waves)
        short8 bh0 = *(short8*)(h2b + ((er * 128 + 0  + gr * 16) ^ swz));
        short8 bh1 = *(short8*)(h2b + ((er * 128 + 64 + gr * 16) ^ swz));

        // ---- L3 + TP, only this wave's half of the channels ----
        #pragma unroll
        for (int jj = 0; jj < 2; ++jj) {
            const int jg = q * 2 + jj;
            ushort4 gsu = jj ? gsu1 : gsu0;
            f32x4 gs4 = {bf2f(gsu.x), bf2f(gsu.y), bf2f(gsu.z), bf2f(gsu.w)};
            f32x4 dA; L3CHUNK(jg, dA);
            f32x4 dB; L3CHUNK(jg + 4, dB);
            #pragma unroll
            for (int r = 0; r < 4; ++r) {
                acc0[jj][r] += 0.125f * dA[r] * gs4[r] * y0;
                float t_ = 0.125f * dB[r] * gs4[r];
                acc2[jj][r][0] += t_ * y1a;
                acc2[jj][r][1] += t_ * y1b;
                acc2[jj][r][2] += t_ * y1c;
            }
        }
        {
            const int jv = q;
            float gv[12] = {bf2f(ga.x), bf2f(ga.y), bf2f(ga.z), bf2f(ga.w),
                            bf2f(gb.x), bf2f(gb.y), bf2f(gb.z), bf2f(gb.w),
                            bf2f(gc.x), bf2f(gc.y), bf2f(gc.z), bf2f(gc.w)};
            f32x4 dC; L3CHUNK(8 + jv, dC);
            f32x4 dD; L3CHUNK(10 + jv, dD);
            #pragma unroll
            for (int r = 0; r < 4; ++r) {
                float w2v = 0.125f * dC[r] * y0;
                acc3[r][0] += w2v * gv[r * 3 + 0];
                acc3[r][1] += w2v * gv[r * 3 + 1];
                acc3[r][2] += w2v * gv[r * 3 + 2];
                float dot = gv[r * 3 + 0] * y1a + gv[r * 3 + 1] * y1b + gv[r * 3 + 2] * y1c;
                acc1[r] += 0.125f * dD[r] * dot * INV3;
            }
        }
    }

    // ---- column reduce (DPP); lane er==15 holds sums ----
    #pragma unroll
    for (int jj = 0; jj < 2; ++jj)
        #pragma unroll
        for (int r = 0; r < 4; ++r) {
            acc0[jj][r] = rowsum16(acc0[jj][r]);
            acc2[jj][r][0] = rowsum16(acc2[jj][r][0]);
            acc2[jj][r][1] = rowsum16(acc2[jj][r][1]);
            acc2[jj][r][2] = rowsum16(acc2[jj][r][2]);
        }
    #pragma unroll
    for (int r = 0; r < 4; ++r) {
        acc1[r] = rowsum16(acc1[r]);
        acc3[r][0] = rowsum16(acc3[r][0]);
        acc3[r][1] = rowsum16(acc3[r][1]);
        acc3[r][2] = rowsum16(acc3[r][2]);
    }

    __syncthreads();   // all K-loop LDS traffic done before mid-row aliasing

    // mid row for node slot ns aliases its h1 region (dead now): 384 floats = 1536 B
    float* m = (float*)(albuf + ns * 4096);
    const float iN = 0.17677669529663687f;   // 1/sqrt(NUM_NEIGHBORS)
    if (er == 15) {
        #pragma unroll
        for (int jj = 0; jj < 2; ++jj) {
            const int jg = q * 2 + jj;
            f32x4 v;
            v[0] = acc0[jj][0] * iN; v[1] = acc0[jj][1] * iN;
            v[2] = acc0[jj][2] * iN; v[3] = acc0[jj][3] * iN;
            *(f32x4*)(m + jg * 16 + gr * 4) = v;
        }
        {
            const int jv = q;
            f32x4 v;
            v[0] = acc1[0] * iN; v[1] = acc1[1] * iN;
            v[2] = acc1[2] * iN; v[3] = acc1[3] * iN;
            *(f32x4*)(m + 64 + jv * 16 + gr * 4) = v;
        }
        #pragma unroll
        for (int jj = 0; jj < 2; ++jj) {
            const int jg = q * 2 + jj;
            float t[12];
            #pragma unroll
            for (int r = 0; r < 4; ++r) {
                t[r * 3 + 0] = acc2[jj][r][0] * iN;
                t[r * 3 + 1] = acc2[jj][r][1] * iN;
                t[r * 3 + 2] = acc2[jj][r][2] * iN;
            }
            float* b = m + 96 + (jg * 16 + gr * 4) * 3;
            *(f32x4*)(b + 0) = (f32x4){t[0], t[1], t[2], t[3]};
            *(f32x4*)(b + 4) = (f32x4){t[4], t[5], t[6], t[7]};
            *(f32x4*)(b + 8) = (f32x4){t[8], t[9], t[10], t[11]};
        }
        {
            const int jv = q;
            float t[12];
            #pragma unroll
            for (int r = 0; r < 4; ++r) {
                t[r * 3 + 0] = acc3[r][0] * iN;
                t[r * 3 + 1] = acc3[r][1] * iN;
                t[r * 3 + 2] = acc3[r][2] * iN;
            }
            float* b = m + 288 + (jv * 16 + gr * 4) * 3;
            *(f32x4*)(b + 0) = (f32x4){t[0], t[1], t[2], t[3]};
            *(f32x4*)(b + 4) = (f32x4){t[4], t[5], t[6], t[7]};
            *(f32x4*)(b + 8) = (f32x4){t[8], t[9], t[10], t[11]};
        }
    }

    __syncthreads();   // mid row complete (written by both waves of the pair)

    // ---- fused linear2 + gate + self-connection; work split across the wave pair ----
    const float a = node_attr[n];
    const float* x = xld[ns];
    const float s96 = a * 0.10206207261596575f;

    float alpha = 0.f;
    for (int i = 0; i < 96; ++i) alpha += m[i] * Wa[i];
    alpha *= s96;

    if (q == 0) {
        float outs = 0.f;
        for (int i = 0; i < 96; ++i) outs += m[i] * Wl2_s[i * 64 + l];
        outs *= s96;
        float scs = 0.f;
        for (int k = 0; k < 64; ++k) scs += x[k] * Wsc0[k * 64 + l];
        scs *= a * 0.125f;
        out[(size_t)n * 160 + l] = scs + alpha * outs;
    } else {
        const float sv = a * 0.17677669529663687f;
        for (int o = l; o < 96; o += 64) {
            int w = o / 3, c = o - w * 3;
            float ov = 0.f;
            for (int u = 0; u < 64; ++u) ov += m[96 + u * 3 + c] * Wl2_v[u * 32 + w];
            for (int u = 0; u < 32; ++u) ov += m[288 + u * 3 + c] * Wl2_v[(64 + u) * 32 + w];
            ov *= s96;
            float scv = 0.f;
            for (int u = 0; u < 32; ++u) scv += x[64 + u * 3 + c] * Wsc1[u * 32 + w];
            scv *= sv;
            out[(size_t)n * 160 + 64 + o] = scv + alpha * ov;
        }
    }
}

extern "C" void kernel_launch(void* const* d_in, const int* in_sizes, int n_in,
                              void* d_out, int out_size, void* d_ws, size_t ws_size,
                              hipStream_t stream) {
    const float* node_input = (const float*)d_in[0];
    const float* node_attr  = (const float*)d_in[1];
    const float* edge_attr  = (const float*)d_in[2];
    const float* esa        = (const float*)d_in[3];
    const float* Wsc0       = (const float*)d_in[4];
    const float* Wsc1       = (const float*)d_in[5];
    const float* Wl1_0      = (const float*)d_in[6];
    const float* Wl1_1      = (const float*)d_in[7];
    const float* Wfc1       = (const float*)d_in[8];
    const float* Wfc2       = (const float*)d_in[9];
    const float* Wfc3       = (const float*)d_in[10];
    const float* Wl2_s      = (const float*)d_in[11];
    const float* Wl2_v      = (const float*)d_in[12];
    const float* Wa         = (const float*)d_in[13];
    const int* edge_src     = (const int*)d_in[14];
    const int* edge_dst     = (const int*)d_in[15];
    float* out = (float*)d_out;

    // ws layout: f_sb (bf16) | f_vb (bf16) | fragbuf | int CSR scratch + perm
    float* ws  = (float*)d_ws;
    unsigned short* f_sb = (unsigned short*)ws;                 // N*64 bf16
    unsigned short* f_vb = (unsigned short*)(ws + 320000);      // N*96 bf16
    uint4* fragbuf = (uint4*)(ws + 1600000);                    // 36*64 uint4
    int* ibuf     = (int*)(ws + 1609216);
    int* deg      = ibuf;            // 10000
    int* gctr     = ibuf + 10000;    // 1 (zeroed with deg)
    int* rowptr   = ibuf + 10016;    // 10000
    int* cursor   = ibuf + 20032;    // 10000
    int* elist    = ibuf + 30080;    // 320000 -> 350080
    int* bcnt     = ibuf + 350080;   // 64
    int* bcur     = ibuf + 350144;   // 64
    int* nodeperm = ibuf + 350208;   // 10000 -> 360208

    hipMemsetAsync(deg, 0, (size_t)(N_NODES + 1) * sizeof(int), stream);
    hipMemsetAsync(bcnt, 0, 64 * sizeof(int), stream);

    // pre_kernel: blocks [0,1250)=hist, [1250,1259)=prep_frags, [1259,3759)=node_l1
    pre_kernel<<<3759, 256, 0, stream>>>(edge_dst, deg, Wfc1, Wfc2, Wfc3, fragbuf,
                                         node_input, node_attr, Wl1_0, Wl1_1, f_sb, f_vb);
    alloc_kernel<<<(N_NODES + 255) / 256, 256, 0, stream>>>(deg, gctr, rowptr, cursor, bcnt);
    bscan_kernel<<<1, 64, 0, stream>>>(bcnt, bcur);
    post_kernel<<<40 + (N_EDGES + 255) / 256, 256, 0, stream>>>(edge_dst, deg, cursor,
                                                                elist, bcur, nodeperm);

    fused_kernel<<<N_NODES / 2, 256, 0, stream>>>(edge_attr, esa, f_sb, f_vb,
                                                  edge_src, elist, rowptr, deg, nodeperm,
                                                  (const float4*)fragbuf,
                                                  node_input, node_attr,
                                                  Wsc0, Wsc1, Wl2_s, Wl2_v, Wa,
                                                  out);
}